// Round 1
// 40.533 us; speedup vs baseline: 1.0649x; 1.0649x over previous
//
#include <hip/hip_runtime.h>
#include <math.h>

#define NBINS 15
#define NBLK  1024          // persistent grid: 4 blocks/CU, 16 waves/CU
#define WPB   4             // waves per block (256 threads)
#define NWAVES (NBLK * WPB) // 4096 waves -> 8 rows/wave at B=32768

// ---------------------------------------------------------------------------
// Fused kernel: one WAVE per row (grid-stride, software-prefetched).
// Per row: max/argmax + sum(exp) via butterfly -> all lanes hold conf/corr;
// lanes 0..44 (t = lane/15, j = lane%15) accumulate soft-bin stats
//   t=0: sum ib, t=1: sum ib*correct, t=2: sum ib*conf   (bin j)
// Block-level fixed-order combine of the 4 waves -> partials[block][45].
// ---------------------------------------------------------------------------
__global__ __launch_bounds__(256) void fused_row_bin_kernel(
    const float* __restrict__ logits, const int* __restrict__ labels,
    float* __restrict__ partials, int B)
{
    const int lane = threadIdx.x & 63;
    const int wid  = threadIdx.x >> 6;
    const int gw   = blockIdx.x * WPB + wid;

    // lane -> (stat t, bin j); boundaries match np.linspace: f32(i * (1/15 in double))
    const int   tsel = lane / 15;               // 0,1,2 for lane<45
    const int   j    = lane - tsel * 15;
    const float lo   = (float)( j      * (1.0 / 15.0));
    const float up   = (float)((j + 1) * (1.0 / 15.0));

    float acc = 0.0f;
    const float NI = -INFINITY;

    // ---- prefetch first row ----
    int row = gw;
    float4 v0, v1, v2, v3;
    int lab = 0;
    if (row < B) {
        const float4* rp = reinterpret_cast<const float4*>(logits + (size_t)row * 1000);
        v0 = rp[lane]; v1 = rp[lane + 64]; v2 = rp[lane + 128];
        v3 = make_float4(NI, NI, NI, NI);
        if (lane < 58) v3 = rp[lane + 192];
        lab = labels[row];
    }

    while (row < B) {
        // ---- issue next row's loads before computing on current ----
        const int nrow = row + NWAVES;
        float4 w0 = make_float4(NI, NI, NI, NI), w1 = w0, w2 = w0, w3 = w0;
        int nlab = 0;
        if (nrow < B) {
            const float4* rp = reinterpret_cast<const float4*>(logits + (size_t)nrow * 1000);
            w0 = rp[lane]; w1 = rp[lane + 64]; w2 = rp[lane + 128];
            if (lane < 58) w3 = rp[lane + 192];
            nlab = labels[nrow];
        }

        // ---- lane-local max/argmax in ascending global-index order ----
        float m = v0.x; int gi = 4 * lane;
        #define CHK(val, idx) do { if ((val) > m) { m = (val); gi = (idx); } } while (0)
        CHK(v0.y, 4 * lane + 1); CHK(v0.z, 4 * lane + 2); CHK(v0.w, 4 * lane + 3);
        CHK(v1.x, 4 * (lane + 64));     CHK(v1.y, 4 * (lane + 64) + 1);
        CHK(v1.z, 4 * (lane + 64) + 2); CHK(v1.w, 4 * (lane + 64) + 3);
        CHK(v2.x, 4 * (lane + 128));     CHK(v2.y, 4 * (lane + 128) + 1);
        CHK(v2.z, 4 * (lane + 128) + 2); CHK(v2.w, 4 * (lane + 128) + 3);
        CHK(v3.x, 4 * (lane + 192));     CHK(v3.y, 4 * (lane + 192) + 1);
        CHK(v3.z, 4 * (lane + 192) + 2); CHK(v3.w, 4 * (lane + 192) + 3);
        #undef CHK

        // butterfly: all lanes converge to row (max, first-argmax)
        #pragma unroll
        for (int off = 1; off < 64; off <<= 1) {
            float om = __shfl_xor(m,  off, 64);
            int   og = __shfl_xor(gi, off, 64);
            if (om > m || (om == m && og < gi)) { m = om; gi = og; }
        }

        // sum of exp(l - max); -inf pads contribute exactly 0
        float s = __expf(v0.x - m) + __expf(v0.y - m) + __expf(v0.z - m) + __expf(v0.w - m)
                + __expf(v1.x - m) + __expf(v1.y - m) + __expf(v1.z - m) + __expf(v1.w - m)
                + __expf(v2.x - m) + __expf(v2.y - m) + __expf(v2.z - m) + __expf(v2.w - m)
                + __expf(v3.x - m) + __expf(v3.y - m) + __expf(v3.z - m) + __expf(v3.w - m);
        #pragma unroll
        for (int off = 1; off < 64; off <<= 1) s += __shfl_xor(s, off, 64);

        const float conf = 1.0f / s;                     // max softmax prob
        const float corr = (gi == lab) ? 1.0f : 0.0f;

        // ---- fused soft-bin accumulation (2 wave-level exps, lanes 0..44) ----
        if (lane < 45) {
            const float s1 = 1.0f / (1.0f + __expf(-20.0f * (conf - lo)));
            const float s2 = 1.0f / (1.0f + __expf(-20.0f * (up - conf)));
            const float ib = s1 * s2;
            const float wgt = (tsel == 0) ? 1.0f : ((tsel == 1) ? corr : conf);
            acc += ib * wgt;
        }

        row = nrow; lab = nlab;
        v0 = w0; v1 = w1; v2 = w2; v3 = w3;
    }

    // ---- fixed-order block combine: partials[block][t*15+j] ----
    __shared__ float part[WPB][45];
    if (lane < 45) part[wid][lane] = acc;
    __syncthreads();
    const int tid = threadIdx.x;
    if (tid < 45) {
        partials[blockIdx.x * 45 + tid] =
            ((part[0][tid] + part[1][tid]) + part[2][tid]) + part[3][tid];
    }
}

// ---------------------------------------------------------------------------
// Finalize: single block, deterministic. 225 threads each sum a fixed
// comb (p ≡ g mod 5) of the NBLK x 45 partials in double; fixed-order
// 5-way combine; per-bin terms; final sum.
// ---------------------------------------------------------------------------
__global__ __launch_bounds__(256) void finalize_kernel(
    const float* __restrict__ partials, float* __restrict__ out, int B)
{
    const int tid = threadIdx.x;
    __shared__ double dpart[5][45];
    if (tid < 225) {
        const int g  = tid / 45;          // 0..4
        const int jj = tid - g * 45;      // 0..44
        double s = 0.0;
        #pragma unroll 8
        for (int p = g; p < NBLK; p += 5) s += (double)partials[p * 45 + jj];
        dpart[g][jj] = s;
    }
    __syncthreads();

    __shared__ double dsum[45];
    if (tid < 45) {
        dsum[tid] = (((dpart[0][tid] + dpart[1][tid]) + dpart[2][tid])
                     + dpart[3][tid]) + dpart[4][tid];
    }
    __syncthreads();

    __shared__ double term[NBINS];
    if (tid < NBINS) {
        const double mass = dsum[tid];
        const double accd = dsum[NBINS + tid]     / (mass + 1e-8);
        const double cfd  = dsum[2 * NBINS + tid] / (mass + 1e-8);
        const double d    = accd - cfd;
        term[tid] = d * d * mass;
    }
    __syncthreads();

    if (tid == 0) {
        double loss = 0.0;
        for (int i = 0; i < NBINS; ++i) loss += term[i];
        out[0] = (float)(loss / (double)B);
    }
}

// ---------------------------------------------------------------------------
// ws layout: partials[NBLK*45] f32  (fully overwritten every launch; no
// counter, no poison sensitivity). 1024*45*4 = 180 KiB < previous ws use.
// ---------------------------------------------------------------------------
extern "C" void kernel_launch(void* const* d_in, const int* in_sizes, int n_in,
                              void* d_out, int out_size, void* d_ws, size_t ws_size,
                              hipStream_t stream)
{
    const float* logits = (const float*)d_in[0];
    const int*   labels = (const int*)d_in[1];
    const int B = in_sizes[1];   // 32768 rows; in_sizes[0]/B == 1000 classes

    float* partials = (float*)d_ws;

    fused_row_bin_kernel<<<NBLK, 256, 0, stream>>>(logits, labels, partials, B);
    finalize_kernel<<<1, 256, 0, stream>>>(partials, (float*)d_out, B);
}

// Round 2
// 32.054 us; speedup vs baseline: 1.3466x; 1.2645x over previous
//
#include <hip/hip_runtime.h>
#include <math.h>

#define NBINS 15
#define NBLK  2048          // 8 blocks/CU on 256 CUs
#define WPB   4             // waves per block (256 threads)
#define NWAVES (NBLK * WPB) // 8192 waves -> 4 rows/wave at B=32768

// ---------------------------------------------------------------------------
// Fused kernel: one WAVE per row (grid-stride). No register double-buffer --
// latency hiding comes from occupancy (8 waves/SIMD, __launch_bounds__(256,8)).
// Per row:
//   max  : v_max3 tree (no index) + 6-stage value-only butterfly
//   argmax: 16 ballots (v_cmp -> SGPR masks) + scalar first-index scan
//   conf : 1 / sum exp(l - M)
//   bins : lanes 0..44 (t = lane/15, j = lane%15) accumulate
//          t=0: sum ib, t=1: sum ib*correct, t=2: sum ib*conf
// Block combine -> partials[j45][block]  (transposed for finalize coalescing).
// ---------------------------------------------------------------------------
__global__ __launch_bounds__(256, 8) void fused_row_bin_kernel(
    const float* __restrict__ logits, const int* __restrict__ labels,
    float* __restrict__ partials, int B)
{
    const int lane = threadIdx.x & 63;
    const int wid  = threadIdx.x >> 6;

    // lane -> (stat t, bin j); boundaries match np.linspace: f32(i * (1/15 in double))
    const int   tsel = lane / 15;
    const int   jb   = lane - tsel * 15;
    const float lo   = (float)( jb      * (1.0 / 15.0));
    const float up   = (float)((jb + 1) * (1.0 / 15.0));

    float acc = 0.0f;
    const float NI = -INFINITY;

    for (int row = blockIdx.x * WPB + wid; row < B; row += NWAVES) {
        const float4* rp = reinterpret_cast<const float4*>(logits + (size_t)row * 1000);
        float4 v0 = rp[lane];
        float4 v1 = rp[lane + 64];
        float4 v2 = rp[lane + 128];
        float4 v3 = make_float4(NI, NI, NI, NI);
        if (lane < 58) v3 = rp[lane + 192];
        const int lab = labels[row];

        // ---- lane-local max (value only), v_max3-friendly triples ----
        float t0 = fmaxf(fmaxf(v0.x, v0.y), v0.z);
        float t1 = fmaxf(fmaxf(v0.w, v1.x), v1.y);
        float t2 = fmaxf(fmaxf(v1.z, v1.w), v2.x);
        float t3 = fmaxf(fmaxf(v2.y, v2.z), v2.w);
        float t4 = fmaxf(fmaxf(v3.x, v3.y), v3.z);
        float m  = fmaxf(fmaxf(fmaxf(t0, t1), fmaxf(t2, t3)), fmaxf(t4, v3.w));

        // value-only butterfly: all lanes get row max M (bit-exact, fmax picks operand)
        #pragma unroll
        for (int off = 1; off < 64; off <<= 1)
            m = fmaxf(m, __shfl_xor(m, off, 64));

        // ---- argmax via ballots: masks are wave-uniform (SGPR), scan is SALU ----
        // element global index for (k, lane l, comp c) = 256*k + 4*l + c
        unsigned long long b00 = __ballot(v0.x == m), b01 = __ballot(v0.y == m);
        unsigned long long b02 = __ballot(v0.z == m), b03 = __ballot(v0.w == m);
        unsigned long long b10 = __ballot(v1.x == m), b11 = __ballot(v1.y == m);
        unsigned long long b12 = __ballot(v1.z == m), b13 = __ballot(v1.w == m);
        unsigned long long b20 = __ballot(v2.x == m), b21 = __ballot(v2.y == m);
        unsigned long long b22 = __ballot(v2.z == m), b23 = __ballot(v2.w == m);
        unsigned long long b30 = __ballot(v3.x == m), b31 = __ballot(v3.y == m);
        unsigned long long b32 = __ballot(v3.z == m), b33 = __ballot(v3.w == m);

        int best = 1 << 30;
        {
            // scan k = 3..0, overwrite: final best = first index (min k, min lane, min c)
            unsigned long long u3 = b30 | b31 | b32 | b33;
            if (u3) {
                int l = __ffsll(u3) - 1;
                int c = ((b30 >> l) & 1) ? 0 : ((b31 >> l) & 1) ? 1 : ((b32 >> l) & 1) ? 2 : 3;
                best = 256 * 3 + 4 * l + c;
            }
            unsigned long long u2 = b20 | b21 | b22 | b23;
            if (u2) {
                int l = __ffsll(u2) - 1;
                int c = ((b20 >> l) & 1) ? 0 : ((b21 >> l) & 1) ? 1 : ((b22 >> l) & 1) ? 2 : 3;
                best = 256 * 2 + 4 * l + c;
            }
            unsigned long long u1 = b10 | b11 | b12 | b13;
            if (u1) {
                int l = __ffsll(u1) - 1;
                int c = ((b10 >> l) & 1) ? 0 : ((b11 >> l) & 1) ? 1 : ((b12 >> l) & 1) ? 2 : 3;
                best = 256 * 1 + 4 * l + c;
            }
            unsigned long long u0 = b00 | b01 | b02 | b03;
            if (u0) {
                int l = __ffsll(u0) - 1;
                int c = ((b00 >> l) & 1) ? 0 : ((b01 >> l) & 1) ? 1 : ((b02 >> l) & 1) ? 2 : 3;
                best = 4 * l + c;
            }
        }
        const float corr = (best == lab) ? 1.0f : 0.0f;

        // ---- sum of exp(l - M); -inf pads contribute exactly 0 ----
        float s = __expf(v0.x - m) + __expf(v0.y - m) + __expf(v0.z - m) + __expf(v0.w - m)
                + __expf(v1.x - m) + __expf(v1.y - m) + __expf(v1.z - m) + __expf(v1.w - m)
                + __expf(v2.x - m) + __expf(v2.y - m) + __expf(v2.z - m) + __expf(v2.w - m)
                + __expf(v3.x - m) + __expf(v3.y - m) + __expf(v3.z - m) + __expf(v3.w - m);
        #pragma unroll
        for (int off = 1; off < 64; off <<= 1) s += __shfl_xor(s, off, 64);

        const float conf = 1.0f / s;   // exp(M-M)=1 over Z

        // ---- fused soft-bin accumulation (lanes 0..44) ----
        if (lane < 45) {
            const float s1 = 1.0f / (1.0f + __expf(-20.0f * (conf - lo)));
            const float s2 = 1.0f / (1.0f + __expf(-20.0f * (up - conf)));
            const float ib = s1 * s2;
            const float wgt = (tsel == 0) ? 1.0f : ((tsel == 1) ? corr : conf);
            acc += ib * wgt;
        }
    }

    // ---- fixed-order block combine -> transposed partials[j][block] ----
    __shared__ float part[WPB][48];      // 48: pad, written once
    if (lane < 45) part[wid][lane] = acc;
    __syncthreads();
    const int tid = threadIdx.x;
    if (tid < 45) {
        partials[(size_t)tid * NBLK + blockIdx.x] =
            ((part[0][tid] + part[1][tid]) + part[2][tid]) + part[3][tid];
    }
}

// ---------------------------------------------------------------------------
// Finalize: one block, 8 waves. Wave w reduces rows j = w, w+8, ... of the
// transposed partials [45][NBLK]: 8 coalesced float4 loads/lane, fixed-order
// double accumulation + fixed-order double butterfly. Deterministic.
// ---------------------------------------------------------------------------
__global__ __launch_bounds__(512) void finalize_kernel(
    const float* __restrict__ partials, float* __restrict__ out, int B)
{
    const int tid  = threadIdx.x;
    const int lane = tid & 63;
    const int wid  = tid >> 6;           // 8 waves

    __shared__ double dsum[45];
    for (int j = wid; j < 45; j += 8) {
        const float4* fp = reinterpret_cast<const float4*>(partials + (size_t)j * NBLK);
        double s = 0.0;
        #pragma unroll
        for (int t = 0; t < NBLK / 256; ++t) {   // 2048/4 float4 = 512 = 64 lanes x 8
            float4 v = fp[lane + 64 * t];
            s += (double)v.x; s += (double)v.y; s += (double)v.z; s += (double)v.w;
        }
        #pragma unroll
        for (int off = 1; off < 64; off <<= 1) s += __shfl_xor(s, off, 64);
        if (lane == 0) dsum[j] = s;
    }
    __syncthreads();

    __shared__ double term[NBINS];
    if (tid < NBINS) {
        const double mass = dsum[tid];
        const double accd = dsum[NBINS + tid]     / (mass + 1e-8);
        const double cfd  = dsum[2 * NBINS + tid] / (mass + 1e-8);
        const double d    = accd - cfd;
        term[tid] = d * d * mass;
    }
    __syncthreads();

    if (tid == 0) {
        double loss = 0.0;
        for (int i = 0; i < NBINS; ++i) loss += term[i];
        out[0] = (float)(loss / (double)B);
    }
}

// ---------------------------------------------------------------------------
// ws layout: partials[45 * NBLK] f32 = 360 KiB (fully overwritten every
// launch; no counters, no poison sensitivity).
// ---------------------------------------------------------------------------
extern "C" void kernel_launch(void* const* d_in, const int* in_sizes, int n_in,
                              void* d_out, int out_size, void* d_ws, size_t ws_size,
                              hipStream_t stream)
{
    const float* logits = (const float*)d_in[0];
    const int*   labels = (const int*)d_in[1];
    const int B = in_sizes[1];   // 32768 rows; in_sizes[0]/B == 1000 classes

    float* partials = (float*)d_ws;

    fused_row_bin_kernel<<<NBLK, 256, 0, stream>>>(logits, labels, partials, B);
    finalize_kernel<<<1, 512, 0, stream>>>(partials, (float*)d_out, B);
}